// Round 18
// baseline (100.541 us; speedup 1.0000x reference)
//
#include <hip/hip_runtime.h>

// NCuts loss: seg [8,4,224,224], padded_seg [8,4,232,232],
// weight [8,1,224,224,9,9], sum_weight [8,1,224,224] -> out[8] (fp32)
//
// R17 stage1 verbatim (512 blocks = 8img x 16rowgrp x 4strips, 14 rows x
// 56 cols, 2 blocks/CU zero-tail, DPP tap loop, weight dbuf global_load_lds
// prefetch, psg window global_load_lds, seg-from-window, wsum recompute,
// XCD swizzle) + FUSED final reduction: last block per image (device-scope
// atomic ticket + threadfence release/acquire) reduces the 64 block-partials
// and writes out[n]. Removes the second kernel launch entirely.
// Ticket counters zeroed per call by a 32B hipMemsetAsync (poison-safe).

constexpr int NN  = 8;
constexpr int KK  = 4;
constexpr int HH  = 224;
constexpr int WW  = 224;
constexpr int PAD = 4;                   // RADIUS-1
constexpr int HP  = HH + 2 * PAD;        // 232
constexpr int WP  = WW + 2 * PAD;        // 232
constexpr int NWIN = 81;
constexpr int PIX = HH * WW;             // 50176
constexpr int TPB = 512;                 // 8 waves
constexpr int PPB = 56;                  // strip width
constexpr int RPB = 14;                  // rows per block
constexpr int CSP = WW / PPB;            // 4 col-strips
constexpr int GPI = HH / RPB;            // 16 row-groups
constexpr int BPI = GPI * CSP;           // 64 blocks per image
constexpr int NBLK = NN * BPI;           // 512 blocks = 2 * 256 CUs
constexpr int PLANE = HP * WP;           // 53824
constexpr int WCOL = PPB + 8;            // 64 window cols
constexpr int NSLOT = RPB + 8;           // 22 window rows
constexpr int PSG_F4 = NSLOT * KK * (WCOL / 4);  // 1408 f4 = 22.5 KB
constexpr int WSLAB = PPB * NWIN;        // 4536 floats per weight tile
constexpr int WF4 = WSLAB / 4;           // 1134 f4

#define GLL16(gptr, lptr)                                            \
    __builtin_amdgcn_global_load_lds(                                \
        (const __attribute__((address_space(1))) void*)(gptr),       \
        (__attribute__((address_space(3))) void*)(lptr), 16, 0, 0)

// lane i <- lane i+1 (zero-fill at lane 63), wave_shl:1 (DppCtrl 0x130)
__device__ __forceinline__ float dpp_shl1(float x) {
    int r = __builtin_amdgcn_update_dpp(
        0, __builtin_bit_cast(int, x), 0x130 /*WAVE_SHL1*/, 0xF, 0xF, true);
    return __builtin_bit_cast(float, r);
}

// full window-row M, all 4 classes, via DPP shifts
template<int M>
__device__ __forceinline__ void do_mrow(const float* __restrict__ lwp,
                                        const float* __restrict__ pbase,
                                        float acc[KK], float& wsum) {
    float wv[9];
#pragma unroll
    for (int j = 0; j < 9; ++j) wv[j] = lwp[9 * M + j];
#pragma unroll
    for (int j = 0; j < 9; ++j) wsum += wv[j];
    float q0 = pbase[(M * KK + 0) * WCOL];
    float q1 = pbase[(M * KK + 1) * WCOL];
    float q2 = pbase[(M * KK + 2) * WCOL];
    float q3 = pbase[(M * KK + 3) * WCOL];
    acc[0] += q0 * wv[0]; acc[1] += q1 * wv[0];
    acc[2] += q2 * wv[0]; acc[3] += q3 * wv[0];
#pragma unroll
    for (int j = 1; j < 9; ++j) {
        q0 = dpp_shl1(q0); q1 = dpp_shl1(q1);
        q2 = dpp_shl1(q2); q3 = dpp_shl1(q3);
        acc[0] += q0 * wv[j]; acc[1] += q1 * wv[j];
        acc[2] += q2 * wv[j]; acc[3] += q3 * wv[j];
    }
}

// single class C of window-row 8 (optionally owns row-8 wsum)
template<int C, bool WSUM8>
__device__ __forceinline__ void do_m8c(const float* __restrict__ lwp,
                                       const float* __restrict__ pbase,
                                       float acc[KK], float& wsum) {
    float wv[9];
#pragma unroll
    for (int j = 0; j < 9; ++j) wv[j] = lwp[72 + j];
    if (WSUM8) {
#pragma unroll
        for (int j = 0; j < 9; ++j) wsum += wv[j];
    }
    float q = pbase[(8 * KK + C) * WCOL];
    acc[C] += q * wv[0];
#pragma unroll
    for (int j = 1; j < 9; ++j) {
        q = dpp_shl1(q);
        acc[C] += q * wv[j];
    }
}

__global__ __launch_bounds__(TPB, 4) void ncuts_fused(
    const float* __restrict__ seg, const float* __restrict__ pseg,
    const float* __restrict__ wgt, const float* __restrict__ swgt,
    float* __restrict__ part, int* __restrict__ cnt,
    float* __restrict__ out)
{
    const int hw   = blockIdx.x;
    const int b    = (hw & 7) * (NBLK / 8) + (hw >> 3);  // XCD swizzle (bijective)
    const int n    = b / BPI;
    const int r    = b - n * BPI;
    const int rg   = r >> 2;                 // row-group 0..15
    const int cs   = r & 3;                  // col-strip 0..3
    const int h0   = rg * RPB;
    const int w0   = cs * PPB;
    const int tid  = threadIdx.x;
    const int wv_  = tid >> 6;               // 0..7
    const int lane = tid & 63;

    __shared__ float lds_w[2 * WSLAB];                 // 36288 B (dbuf)
    __shared__ float psg_lds[NSLOT * KK * WCOL];       // 22528 B
    __shared__ float lred[8][8];                       // 256 B
    __shared__ int   is_last;

    const size_t nb = (size_t)n * KK * PLANE;

    // ---- weight tile stager (R13/R15-proven) ----
    auto stage_w = [&](int buf, int s) {
        const float4* wsrc = (const float4*)(
            wgt + ((size_t)n * PIX + (size_t)(h0 + s) * WW + w0) * NWIN);
        float* base = lds_w + buf * WSLAB;
#pragma unroll
        for (int k = 0; k < 3; ++k) {
            const int i = k * TPB + tid;
            if (i < WF4)
                GLL16(wsrc + i, base + ((k * TPB + (tid & ~63)) << 2));
        }
    };

    stage_w(0, 0);                            // async: weight tile 0

    // ---- psg window prologue: [22 slots][4 cls][64 cols], 1408 f4 ----
#pragma unroll
    for (int k = 0; k < 3; ++k) {
        const int i = k * TPB + tid;
        if (i < PSG_F4) {
            const int slot = i >> 6;              // 64 f4 per slot
            const int c    = (i >> 4) & 3;
            const int c4   = i & 15;
            const float* src = pseg + nb + (size_t)c * PLANE +
                               (size_t)(h0 + slot) * WP + w0 + c4 * 4;
            GLL16(src, psg_lds + ((k * TPB + (tid & ~63)) << 2));
        }
    }

    float rA[KK] = {0.f, 0.f, 0.f, 0.f};
    float rV[KK] = {0.f, 0.f, 0.f, 0.f};

    __syncthreads();   // psg window + weight tile 0 landed

    const int wlane = (lane < PPB) ? lane : (PPB - 1);   // clamp for w-reads

    int cur = 0;
#pragma unroll 1
    for (int s = 0; s < RPB; ++s) {
        // ---- prefetch next row-tile's weights into the other buffer ----
        if (s + 1 < RPB) stage_w(cur ^ 1, s + 1);

        // ---- compute row s: ALL 64 lanes (DPP needs full exec) ----
        {
            const float* lwp   = lds_w + cur * WSLAB + wlane * NWIN;
            const float* pbase = psg_lds + (size_t)s * KK * WCOL + lane;
            float acc[KK] = {0.f, 0.f, 0.f, 0.f};
            float wsum = 0.f;
            switch (wv_) {
                case 0: do_mrow<0>(lwp, pbase, acc, wsum);
                        do_m8c<0, true>(lwp, pbase, acc, wsum);  break;
                case 1: do_mrow<1>(lwp, pbase, acc, wsum);
                        do_m8c<1, false>(lwp, pbase, acc, wsum); break;
                case 2: do_mrow<2>(lwp, pbase, acc, wsum);
                        do_m8c<2, false>(lwp, pbase, acc, wsum); break;
                case 3: do_mrow<3>(lwp, pbase, acc, wsum);
                        do_m8c<3, false>(lwp, pbase, acc, wsum); break;
                case 4: do_mrow<4>(lwp, pbase, acc, wsum); break;
                case 5: do_mrow<5>(lwp, pbase, acc, wsum); break;
                case 6: do_mrow<6>(lwp, pbase, acc, wsum); break;
                default: do_mrow<7>(lwp, pbase, acc, wsum); break;
            }
            if (lane < PPB) {
                float segv[KK];
#pragma unroll
                for (int c = 0; c < KK; ++c)      // seg = window interior
                    segv[c] = pbase[((4 * KK) + c) * WCOL + 4];
#pragma unroll
                for (int c = 0; c < KK; ++c) {
                    rA[c] += acc[c] * segv[c];
                    rV[c] += wsum   * segv[c];
                }
            }
        }
        __syncthreads();   // tile consumed; prefetch drained (overlap across
        cur ^= 1;          //   the 2 resident blocks + 8 waves on this CU)
    }

    // ---- block reduction -> part[b] ----
    float vals[8] = { rA[0], rA[1], rA[2], rA[3], rV[0], rV[1], rV[2], rV[3] };
#pragma unroll
    for (int i = 0; i < 8; ++i) {
        float v = vals[i];
#pragma unroll
        for (int off = 32; off > 0; off >>= 1) v += __shfl_down(v, off, 64);
        if (lane == 0) lred[wv_][i] = v;
    }
    __syncthreads();
    if (tid < 8) {
        float ssum = 0.f;
#pragma unroll
        for (int w = 0; w < 8; ++w) ssum += lred[w][tid];
        part[(size_t)(n * BPI + (r)) * 8 + tid] = ssum;   // image-major index
    }

    // ---- fused finish: last block of image n reduces all 64 partials ----
    __threadfence();                      // release: part[] visible device-wide
    __syncthreads();
    if (tid == 0) {
        const int ticket = atomicAdd(&cnt[n], 1);
        is_last = (ticket == BPI - 1);
    }
    __syncthreads();
    if (is_last && wv_ == 0) {
        __threadfence();                  // acquire: see all 64 blocks' part[]
        float v[8];
#pragma unroll
        for (int i = 0; i < 8; ++i)
            v[i] = part[(size_t)(n * BPI + lane) * 8 + i];   // lane = block
#pragma unroll
        for (int i = 0; i < 8; ++i) {
#pragma unroll
            for (int off = 32; off > 0; off >>= 1)
                v[i] += __shfl_down(v[i], off, 64);
        }
        if (lane == 0) {
            float assoc = 0.f;
#pragma unroll
            for (int k = 0; k < 4; ++k) assoc += v[k] / v[4 + k];
            out[n] = 4.0f - assoc;
        }
    }
}

extern "C" void kernel_launch(void* const* d_in, const int* in_sizes, int n_in,
                              void* d_out, int out_size, void* d_ws, size_t ws_size,
                              hipStream_t stream) {
    const float* seg  = (const float*)d_in[0];
    const float* pseg = (const float*)d_in[1];
    const float* wgt  = (const float*)d_in[2];
    const float* swgt = (const float*)d_in[3];
    float* out  = (float*)d_out;
    float* part = (float*)d_ws;                       // 512*8 floats = 16384 B
    int*   cnt  = (int*)((char*)d_ws + 512 * 8 * 4);  // 8 ints

    hipMemsetAsync(cnt, 0, NN * sizeof(int), stream); // poison-safe ticket init
    ncuts_fused<<<NBLK, TPB, 0, stream>>>(seg, pseg, wgt, swgt, part, cnt, out);
}

// Round 19
// 32.575 us; speedup vs baseline: 3.0865x; 3.0865x over previous
//
#include <hip/hip_runtime.h>

// NCuts loss: seg [8,4,224,224], padded_seg [8,4,232,232],
// weight [8,1,224,224,9,9], sum_weight [8,1,224,224] -> out[8] (fp32)
//
// R17 structure verbatim (512 blocks = 8img x 16rowgrp x 4strips, 14 rows
// x 56 cols, 2 blocks/CU zero-tail, DPP tap loop, psg window
// global_load_lds, seg-from-window, wsum recompute, XCD swizzle, separate
// tiny stage2) with ONE isolated change -- counted-vmcnt weight pipeline:
//  - weight stager: per-wave CONTIGUOUS 142-f4 chunk (wave7: 140), exactly
//    3 GLL16/wave/tile, zero padding (R11's padded variant added +35%
//    DMA bytes; this adds none).
//  - loop: {issue next tile; s_waitcnt vmcnt(3); s_barrier; compute;
//    s_barrier}. The prefetch stays IN FLIGHT across the barrier --
//    __syncthreads' vmcnt(0) drain (the documented ~20% stall) is gone
//    from the steady state; vmcnt(0) only on the last tile.
//  - compute phase issues no global ops, so vmcnt counts are exact.
// R18's fused threadfence reduction regressed 3x (device-scope fence =
// cross-XCD L2 writeback) and is reverted.

constexpr int NN  = 8;
constexpr int KK  = 4;
constexpr int HH  = 224;
constexpr int WW  = 224;
constexpr int PAD = 4;                   // RADIUS-1
constexpr int HP  = HH + 2 * PAD;        // 232
constexpr int WP  = WW + 2 * PAD;        // 232
constexpr int NWIN = 81;
constexpr int PIX = HH * WW;             // 50176
constexpr int TPB = 512;                 // 8 waves
constexpr int PPB = 56;                  // strip width
constexpr int RPB = 14;                  // rows per block
constexpr int CSP = WW / PPB;            // 4 col-strips
constexpr int GPI = HH / RPB;            // 16 row-groups
constexpr int BPI = GPI * CSP;           // 64 blocks per image
constexpr int NBLK = NN * BPI;           // 512 blocks = 2 * 256 CUs
constexpr int PLANE = HP * WP;           // 53824
constexpr int WCOL = PPB + 8;            // 64 window cols
constexpr int NSLOT = RPB + 8;           // 22 window rows
constexpr int PSG_F4 = NSLOT * KK * (WCOL / 4);  // 1408 f4 = 22.5 KB
constexpr int WSLAB = PPB * NWIN;        // 4536 floats per weight tile
constexpr int WF4 = WSLAB / 4;           // 1134 f4
constexpr int CW  = 142;                 // f4 chunk per wave (wave 7: 140)

#define GLL16(gptr, lptr)                                            \
    __builtin_amdgcn_global_load_lds(                                \
        (const __attribute__((address_space(1))) void*)(gptr),       \
        (__attribute__((address_space(3))) void*)(lptr), 16, 0, 0)

// lane i <- lane i+1 (zero-fill at lane 63), wave_shl:1 (DppCtrl 0x130)
__device__ __forceinline__ float dpp_shl1(float x) {
    int r = __builtin_amdgcn_update_dpp(
        0, __builtin_bit_cast(int, x), 0x130 /*WAVE_SHL1*/, 0xF, 0xF, true);
    return __builtin_bit_cast(float, r);
}

// full window-row M, all 4 classes, via DPP shifts
template<int M>
__device__ __forceinline__ void do_mrow(const float* __restrict__ lwp,
                                        const float* __restrict__ pbase,
                                        float acc[KK], float& wsum) {
    float wv[9];
#pragma unroll
    for (int j = 0; j < 9; ++j) wv[j] = lwp[9 * M + j];
#pragma unroll
    for (int j = 0; j < 9; ++j) wsum += wv[j];
    float q0 = pbase[(M * KK + 0) * WCOL];
    float q1 = pbase[(M * KK + 1) * WCOL];
    float q2 = pbase[(M * KK + 2) * WCOL];
    float q3 = pbase[(M * KK + 3) * WCOL];
    acc[0] += q0 * wv[0]; acc[1] += q1 * wv[0];
    acc[2] += q2 * wv[0]; acc[3] += q3 * wv[0];
#pragma unroll
    for (int j = 1; j < 9; ++j) {
        q0 = dpp_shl1(q0); q1 = dpp_shl1(q1);
        q2 = dpp_shl1(q2); q3 = dpp_shl1(q3);
        acc[0] += q0 * wv[j]; acc[1] += q1 * wv[j];
        acc[2] += q2 * wv[j]; acc[3] += q3 * wv[j];
    }
}

// single class C of window-row 8 (optionally owns row-8 wsum)
template<int C, bool WSUM8>
__device__ __forceinline__ void do_m8c(const float* __restrict__ lwp,
                                       const float* __restrict__ pbase,
                                       float acc[KK], float& wsum) {
    float wv[9];
#pragma unroll
    for (int j = 0; j < 9; ++j) wv[j] = lwp[72 + j];
    if (WSUM8) {
#pragma unroll
        for (int j = 0; j < 9; ++j) wsum += wv[j];
    }
    float q = pbase[(8 * KK + C) * WCOL];
    acc[C] += q * wv[0];
#pragma unroll
    for (int j = 1; j < 9; ++j) {
        q = dpp_shl1(q);
        acc[C] += q * wv[j];
    }
}

__global__ __launch_bounds__(TPB, 4) void ncuts_stage1(
    const float* __restrict__ seg, const float* __restrict__ pseg,
    const float* __restrict__ wgt, const float* __restrict__ swgt,
    float* __restrict__ part)
{
    const int hw   = blockIdx.x;
    const int b    = (hw & 7) * (NBLK / 8) + (hw >> 3);  // XCD swizzle (bijective)
    const int n    = b / BPI;
    const int r    = b - n * BPI;
    const int rg   = r >> 2;                 // row-group 0..15
    const int cs   = r & 3;                  // col-strip 0..3
    const int h0   = rg * RPB;
    const int w0   = cs * PPB;
    const int tid  = threadIdx.x;
    const int wv_  = tid >> 6;               // 0..7
    const int lane = tid & 63;

    __shared__ float lds_w[2 * WSLAB];                 // 36288 B (dbuf)
    __shared__ float psg_lds[NSLOT * KK * WCOL];       // 22528 B
    __shared__ float lred[8][8];                       // 256 B -> 59072 B

    const size_t nb = (size_t)n * KK * PLANE;

    // ---- weight stager: per-wave contiguous chunk, EXACTLY 3 GLL16/wave ----
    const int cbase = wv_ * CW;                         // chunk start (f4)
    const int clen  = (wv_ == 7) ? (WF4 - 7 * CW) : CW; // 140 or 142
    auto stage_w = [&](int buf, int s) {
        const float4* wsrc = (const float4*)(
            wgt + ((size_t)n * PIX + (size_t)(h0 + s) * WW + w0) * NWIN);
        float* base = lds_w + buf * WSLAB;
#pragma unroll
        for (int k = 0; k < 3; ++k) {
            const int o = k * 64 + lane;                // offset within chunk
            if (o < clen)                               // exec nonzero each k
                GLL16(wsrc + cbase + o, base + ((cbase + k * 64) << 2));
        }
    };

    stage_w(0, 0);                            // async: weight tile 0

    // ---- psg window prologue: [22 slots][4 cls][64 cols], 1408 f4 ----
#pragma unroll
    for (int k = 0; k < 3; ++k) {
        const int i = k * TPB + tid;
        if (i < PSG_F4) {
            const int slot = i >> 6;              // 64 f4 per slot
            const int c    = (i >> 4) & 3;
            const int c4   = i & 15;
            const float* src = pseg + nb + (size_t)c * PLANE +
                               (size_t)(h0 + slot) * WP + w0 + c4 * 4;
            GLL16(src, psg_lds + ((k * TPB + (tid & ~63)) << 2));
        }
    }

    float rA[KK] = {0.f, 0.f, 0.f, 0.f};
    float rV[KK] = {0.f, 0.f, 0.f, 0.f};

    __syncthreads();   // prologue-only full drain: psg + weight tile 0 landed

    const int wlane = (lane < PPB) ? lane : (PPB - 1);   // clamp for w-reads

    int cur = 0;
#pragma unroll 1
    for (int s = 0; s < RPB; ++s) {
        // ---- issue next tile's DMA, counted wait on current tile ----
        if (s + 1 < RPB) {
            stage_w(cur ^ 1, s + 1);
            asm volatile("s_waitcnt vmcnt(3)" ::: "memory");  // tile s landed
        } else {
            asm volatile("s_waitcnt vmcnt(0)" ::: "memory");  // last tile
        }
        __builtin_amdgcn_s_barrier();         // all waves' tile s visible

        // ---- compute row s: ALL 64 lanes (DPP needs full exec) ----
        {
            const float* lwp   = lds_w + cur * WSLAB + wlane * NWIN;
            const float* pbase = psg_lds + (size_t)s * KK * WCOL + lane;
            float acc[KK] = {0.f, 0.f, 0.f, 0.f};
            float wsum = 0.f;
            switch (wv_) {
                case 0: do_mrow<0>(lwp, pbase, acc, wsum);
                        do_m8c<0, true>(lwp, pbase, acc, wsum);  break;
                case 1: do_mrow<1>(lwp, pbase, acc, wsum);
                        do_m8c<1, false>(lwp, pbase, acc, wsum); break;
                case 2: do_mrow<2>(lwp, pbase, acc, wsum);
                        do_m8c<2, false>(lwp, pbase, acc, wsum); break;
                case 3: do_mrow<3>(lwp, pbase, acc, wsum);
                        do_m8c<3, false>(lwp, pbase, acc, wsum); break;
                case 4: do_mrow<4>(lwp, pbase, acc, wsum); break;
                case 5: do_mrow<5>(lwp, pbase, acc, wsum); break;
                case 6: do_mrow<6>(lwp, pbase, acc, wsum); break;
                default: do_mrow<7>(lwp, pbase, acc, wsum); break;
            }
            if (lane < PPB) {
                float segv[KK];
#pragma unroll
                for (int c = 0; c < KK; ++c)      // seg = window interior
                    segv[c] = pbase[((4 * KK) + c) * WCOL + 4];
#pragma unroll
                for (int c = 0; c < KK; ++c) {
                    rA[c] += acc[c] * segv[c];
                    rV[c] += wsum   * segv[c];
                }
            }
        }
        __builtin_amdgcn_s_barrier();         // buf cur fully consumed before
        cur ^= 1;                             //   next iter's DMA overwrites it
    }

    // ---- single block-end reduction ----
    float vals[8] = { rA[0], rA[1], rA[2], rA[3], rV[0], rV[1], rV[2], rV[3] };
#pragma unroll
    for (int i = 0; i < 8; ++i) {
        float v = vals[i];
#pragma unroll
        for (int off = 32; off > 0; off >>= 1) v += __shfl_down(v, off, 64);
        if (lane == 0) lred[wv_][i] = v;
    }
    __syncthreads();
    if (tid < 8) {
        float ssum = 0.f;
#pragma unroll
        for (int w = 0; w < 8; ++w) ssum += lred[w][tid];
        part[(size_t)b * 8 + tid] = ssum;
    }
}

__global__ __launch_bounds__(256) void ncuts_stage2(
    const float* __restrict__ part, float* __restrict__ out)
{
    const int n   = blockIdx.x;
    const int tid = threadIdx.x;

    float vals[8] = {0.f, 0.f, 0.f, 0.f, 0.f, 0.f, 0.f, 0.f};
    for (int bb = tid; bb < BPI; bb += 256) {       // 64 entries per image
        const float* q = part + ((size_t)(n * BPI + bb)) * 8;
#pragma unroll
        for (int i = 0; i < 8; ++i) vals[i] += q[i];
    }

    __shared__ float lred[4][8];
    const int lane = tid & 63;
    const int wv_  = tid >> 6;
#pragma unroll
    for (int i = 0; i < 8; ++i) {
        float v = vals[i];
#pragma unroll
        for (int off = 32; off > 0; off >>= 1) v += __shfl_down(v, off, 64);
        if (lane == 0) lred[wv_][i] = v;
    }
    __syncthreads();
    if (tid == 0) {
        float assoc = 0.f;
#pragma unroll
        for (int k = 0; k < 4; ++k) {
            const float A = lred[0][k] + lred[1][k] + lred[2][k] + lred[3][k];
            const float V = lred[0][4 + k] + lred[1][4 + k] + lred[2][4 + k] + lred[3][4 + k];
            assoc += A / V;
        }
        out[n] = 4.0f - assoc;
    }
}

extern "C" void kernel_launch(void* const* d_in, const int* in_sizes, int n_in,
                              void* d_out, int out_size, void* d_ws, size_t ws_size,
                              hipStream_t stream) {
    const float* seg  = (const float*)d_in[0];
    const float* pseg = (const float*)d_in[1];
    const float* wgt  = (const float*)d_in[2];
    const float* swgt = (const float*)d_in[3];
    float* out  = (float*)d_out;
    float* part = (float*)d_ws;   // 512 blocks * 8 floats = 16384 B

    ncuts_stage1<<<NBLK, TPB, 0, stream>>>(seg, pseg, wgt, swgt, part);
    ncuts_stage2<<<NN, 256, 0, stream>>>(part, out);
}